// Round 13
// baseline (212.968 us; speedup 1.0000x reference)
//
#include <hip/hip_runtime.h>
#include <stdint.h>

// ---------------------------------------------------------------------------
// MultiAttentionHead: B=4 S=1024 E=1024 H=16 D=64, fp32 in/out.
// R10: ALL-FP16 single-pass pipeline. R13: BARRIER-FREE k_attn -- R11/R12
// post-mortems showed ~6000 cyc/block-iter vs ~600 static: every
// __syncthreads drains vmcnt(0) block-wide (m97 semantics), serializing all
// waves on the slowest DMA each iteration. Fix: NO LDS staging for Q/K/V --
// MFMA fragments load DIRECTLY from global into registers (per-register
// vmcnt scheduling, waves slip independently, TLP hides L2/L3 latency).
// Only LDS use: wave-private P round-trip (stride-72 pad, intra-wave
// lgkmcnt). Zero barriers in the t-loop. LDS 48->10 KB.
// Attention: QK = q*k (q pre-scaled 0.125*log2e), static softmax p=exp2(s)
// (f16-rounded for PV; l sums unrounded e), PV = p*v. Rows s >= len[b]:
// uniform attn = mean(V) via vsum (fp32, from projection accumulators).
// Carried: R1 XOR swizzle in k_proj (0 conflicts), R4 static softmax,
// R8 LDS-staged epilogue + direct V^T + fused prep, R11 balance remap.
// R9 post-mortem: k_proj BK=32 dbuf regressed -> keeps BK=64 2-barrier.
// ---------------------------------------------------------------------------

using u16     = unsigned short;
using half8   = __attribute__((ext_vector_type(8))) _Float16;
using floatx4 = __attribute__((ext_vector_type(4))) float;

#define MFMA16(a, b, c) __builtin_amdgcn_mfma_f32_16x16x32_f16(a, b, c, 0, 0, 0)

__device__ __forceinline__ u16 f2h(float f) {  // f32 -> f16 bits (RTN)
  _Float16 h = (_Float16)f; u16 u; __builtin_memcpy(&u, &h, 2); return u;
}

// DPP rotate within aligned 16-lane rows (pure VALU; no LDS pipe).
template <int CTRL>
__device__ __forceinline__ float dppf(float v) {
  return __int_as_float(__builtin_amdgcn_update_dpp(
      0, __float_as_int(v), CTRL, 0xF, 0xF, true));
}
__device__ __forceinline__ float rowsum16(float v) {  // all-reduce sum, 16 lanes
  v += dppf<0x121>(v);
  v += dppf<0x122>(v);
  v += dppf<0x124>(v);
  v += dppf<0x128>(v);
  return v;
}

// async global->LDS DMA, 16B per lane (k_proj staging only).
__device__ __forceinline__ void async_cp16(void* lds, const void* g) {
  __builtin_amdgcn_global_load_lds(
      (__attribute__((address_space(1))) uint32_t*)(uintptr_t)g,
      (__attribute__((address_space(3))) uint32_t*)(uint32_t)(uintptr_t)lds,
      16, 0, 0);
}

// ---------------------------------------------------------------------------
// 1) prep (fused): blocks [0,4096): x -> f16 (block 0 zeroes vsum);
//    blocks [4096,7168): transpose W -> WT[n][k] f16.
// ---------------------------------------------------------------------------
__global__ void k_prep(const float* __restrict__ x, u16* __restrict__ xh,
                       const float* __restrict__ w0, const float* __restrict__ w1,
                       const float* __restrict__ w2,
                       u16* __restrict__ o0, u16* __restrict__ o1,
                       u16* __restrict__ o2, float* __restrict__ vsum) {
  __shared__ float t[32][33];
  const int bx = blockIdx.x;
  if (bx < 4096) {
    int i = (bx * 256 + threadIdx.x) * 4;
    float4 v = *(const float4*)(x + i);
    ushort4 hv;
    hv.x = f2h(v.x);
    hv.y = f2h(v.y);
    hv.z = f2h(v.z);
    hv.w = f2h(v.w);
    *(ushort4*)(xh + i) = hv;
    if (bx == 0) {  // zero vsum (4096 floats) for k_proj's atomics
      float4 z = {0.f, 0.f, 0.f, 0.f};
#pragma unroll
      for (int e = 0; e < 4; e++) ((float4*)vsum)[threadIdx.x * 4 + e] = z;
    }
    return;
  }
  const int id = bx - 4096;                 // 0..3071
  const int z = id >> 10, rem = id & 1023;
  const float* W = z == 0 ? w0 : (z == 1 ? w1 : w2);
  u16* oh = z == 0 ? o0 : (z == 1 ? o1 : o2);
  const int kb = (rem & 31) * 32, nb = (rem >> 5) * 32;
  const int tx = threadIdx.x & 31, ty = threadIdx.x >> 5;
  for (int r = ty; r < 32; r += 8) t[r][tx] = W[(kb + r) * 1024 + nb + tx];
  __syncthreads();
  for (int r = ty; r < 32; r += 8)
    oh[(nb + r) * 1024 + kb + tx] = f2h(t[tx][r]);
}

// ---------------------------------------------------------------------------
// 2) projection GEMM: C[4096][1024] = xh @ Wh + b, fp16 single pass,
//    128x128 tile, BK=64, 2-barrier K-loop (R9: dbuf regresses here).
//    LDS 32 KB staging / 34.8 KB epilogue tile -> 4 blocks/CU. Epilogue
//    stages C through LDS ([128][136]) for 16B stores. z=0/1 -> q/k f16 in
//    [B][H][S][D] (q pre-scaled by 0.125*log2e); z=2 -> V^T f16 + vsum.
// ---------------------------------------------------------------------------
__launch_bounds__(256, 4)
__global__ void k_proj(const u16* __restrict__ xh,
                       const u16* __restrict__ wqT, const u16* __restrict__ wkT,
                       const u16* __restrict__ wvT,
                       const float* __restrict__ bq, const float* __restrict__ bk,
                       const float* __restrict__ bv,
                       u16* __restrict__ qh, u16* __restrict__ kh,
                       u16* __restrict__ vth, float* __restrict__ vsum) {
  __shared__ u16 Sm[17408];  // K-loop: A@0, B@8192 ([128][64] f16 = 16 KB ea);
                             // epilogue: C tile [128][136] (34816 B)
  const int z = blockIdx.z;
  const u16* wT = z == 0 ? wqT : (z == 1 ? wkT : wvT);
  const float* bias = z == 0 ? bq : (z == 1 ? bk : bv);
  u16* oh = z == 0 ? qh : (z == 1 ? kh : vth);
  const float oscale = (z == 0) ? 0.18033688011112042f : 1.0f;  // 0.125*log2(e)

  const int tid = threadIdx.x, l = tid & 63, w = tid >> 6;
  const int quad = l >> 4, col = l & 15;
  const int m0 = blockIdx.x * 128, n0 = blockIdx.y * 128;
  const int wm = (w & 1) * 64, wn = (w >> 1) * 64;

  const int row0 = tid >> 3, ch = tid & 7;
  const int sc8 = (ch ^ (row0 & 7)) * 8;
  int gofs[4], lofs[4];
#pragma unroll
  for (int p = 0; p < 4; p++) {
    gofs[p] = (row0 + 32 * p) * 1024 + sc8;
    lofs[p] = (tid + p * 256) * 8;
  }

  const u16* Ag = xh + m0 * 1024;
  const u16* Bg = wT + n0 * 1024;

  int ar[2][4], br[2][4];
#pragma unroll
  for (int ks = 0; ks < 2; ks++) {
#pragma unroll
    for (int i = 0; i < 4; i++) {
      int r = wm + i * 16 + col;
      ar[ks][i] = r * 64 + (((ks * 4 + quad) ^ (r & 7)) * 8);
    }
#pragma unroll
    for (int j = 0; j < 4; j++) {
      int r = wn + j * 16 + col;
      br[ks][j] = r * 64 + (((ks * 4 + quad) ^ (r & 7)) * 8);
    }
  }

  floatx4 zero4 = {0.f, 0.f, 0.f, 0.f};
  floatx4 acc[4][4];
#pragma unroll
  for (int i = 0; i < 4; i++)
#pragma unroll
    for (int j = 0; j < 4; j++) acc[i][j] = zero4;

  for (int k0 = 0; k0 < 1024; k0 += 64) {
    __syncthreads();  // previous compute done before LDS overwrite
#pragma unroll
    for (int p = 0; p < 4; p++) async_cp16(Sm + lofs[p], Ag + gofs[p] + k0);
#pragma unroll
    for (int p = 0; p < 4; p++)
      async_cp16(Sm + 8192 + lofs[p], Bg + gofs[p] + k0);
    __syncthreads();  // DMA drained

#pragma unroll
    for (int ks = 0; ks < 2; ks++) {
      half8 fa[4], fb[4];
#pragma unroll
      for (int i = 0; i < 4; i++) fa[i] = *(const half8*)(Sm + ar[ks][i]);
#pragma unroll
      for (int j = 0; j < 4; j++)
        fb[j] = *(const half8*)(Sm + 8192 + br[ks][j]);
#pragma unroll
      for (int i = 0; i < 4; i++)
#pragma unroll
        for (int j = 0; j < 4; j++) acc[i][j] = MFMA16(fa[i], fb[j], acc[i][j]);
    }
  }

  // ---- epilogue: stage C tile in LDS ([128][136]) for coalesced stores ----
  const int bidx = m0 >> 10;     // batch index
  const int sbase = m0 & 1023;
  __syncthreads();  // all K-loop LDS reads done before overwrite

#pragma unroll
  for (int j = 0; j < 4; j++) {
    int nloc = wn + j * 16 + col;
    float bb = bias[n0 + nloc];
#pragma unroll
    for (int i = 0; i < 4; i++)
#pragma unroll
      for (int r = 0; r < 4; r++) {
        int mloc = wm + i * 16 + quad * 4 + r;
        Sm[mloc * 136 + nloc] = f2h((acc[i][j][r] + bb) * oscale);
      }
  }
  __syncthreads();

  if (z != 2) {
    // q/k: [bh][s][64] -- row-contiguous 16B chunks
#pragma unroll
    for (int k = 0; k < 8; k++) {
      int c = tid + k * 256;
      int mloc = c >> 4, n = (c & 15) * 8;
      int hh = (n0 + n) >> 6, d = (n0 + n) & 63;
      half8 vv = *(const half8*)(Sm + mloc * 136 + n);
      *(half8*)(oh + ((bidx * 16 + hh) * 1024 + sbase + mloc) * 64 + d) = vv;
    }
  } else {
    // V^T: [bh][d][1024] -- transposed read, s-contiguous 16B stores
#pragma unroll
    for (int k = 0; k < 8; k++) {
      int c = tid + k * 256;
      int nloc = c & 127, s0 = (c >> 7) * 8;
      int hh = (n0 + nloc) >> 6, d = (n0 + nloc) & 63;
      u16 tmp[8];
#pragma unroll
      for (int e = 0; e < 8; e++) tmp[e] = Sm[(s0 + e) * 136 + nloc];
      *(half8*)(vth + ((bidx * 16 + hh) * 64 + d) * 1024 + sbase + s0) =
          *(half8*)tmp;
    }
    // vsum partials from fp32 acc: vsum[bh*64+d] += sum over this block's s
#pragma unroll
    for (int j = 0; j < 4; j++) {
      int nloc = wn + j * 16 + col;
      float bb = bias[n0 + nloc];
      float part = 16.0f * bb;
#pragma unroll
      for (int i = 0; i < 4; i++)
#pragma unroll
        for (int r = 0; r < 4; r++) part += acc[i][j][r];
      part += __shfl_xor(part, 16, 64);  // reduce across quads (same n)
      part += __shfl_xor(part, 32, 64);
      if (quad == 0) {
        int hh = (n0 + nloc) >> 6, d = (n0 + nloc) & 63;
        unsafeAtomicAdd(vsum + (bidx * 16 + hh) * 64 + d, part);
      }
    }
  }
}

// ---------------------------------------------------------------------------
// 3) flash attention, fp16, static softmax, BARRIER-FREE (R13).
//    Block: one (b,h), 64 q-rows; wave w owns rows w*16..w*16+15.
//    Per t-tile of 64: K B-frags and V B-frags load DIRECTLY from global
//    (per-lane 16B, register dest -> compiler fine-grained vmcnt; waves
//    independent). V loads issued before softmax to pre-hide latency.
//    P round-trip via wave-private LDS rows ([16][72] pad per wave,
//    intra-wave lgkmcnt only). NO __syncthreads in the loop.
//    LDS 10 KB; occupancy VGPR-bound. Grid 1024, R11 balance remap.
// ---------------------------------------------------------------------------
__launch_bounds__(256)
__global__ void k_attn(const u16* __restrict__ qh_g,
                       const u16* __restrict__ kh_g,
                       const u16* __restrict__ vth_g,
                       const float* __restrict__ vsum, const int* __restrict__ elen,
                       float* __restrict__ out) {
  __shared__ u16 P[4 * 1280];  // per-wave [16 q][72 t] (pad), wave-private
  const int tid = threadIdx.x, l = tid & 63, w = tid >> 6;
  const int quad = l >> 4, col = l & 15;
  // R11 balance remap: each CU's stride-256 resident set spans all 4 batches
  const int id = blockIdx.x;
  const int b = (id + (id >> 8)) & 3;
  const int h = (id >> 2) & 15;
  const int bh = b * 16 + h;
  const int q0 = ((id >> 6) & 15) * 64;
  const int len = elen[b];

  if (q0 >= len) {  // fully-invalid tile: uniform attention over ALL t (ref)
    float val = vsum[bh * 64 + l] * (1.0f / 1024.0f);
    float* op = out + (b * 1024 + q0) * 1024 + h * 64 + l;
    for (int r = w; r < 64; r += 4) op[r * 1024] = val;
    return;
  }

  // Q A-frags direct from global (m = lane&15 -> q-row, k = ks*32+quad*8)
  half8 qf[2];
  {
    const u16* qb = qh_g + (bh * 1024 + q0 + w * 16 + col) * 64 + quad * 8;
    qf[0] = *(const half8*)(qb);
    qf[1] = *(const half8*)(qb + 32);
  }

  const u16* kb_g = kh_g + bh * 65536;   // [t][64]
  const u16* vb_g = vth_g + bh * 65536;  // [d][1024]

  u16* Pw = P + w * 1280;
  const int p_rd0 = col * 72 + quad * 8;             // + ks*32
  const int p_wb = (quad * 4) * 72 + col;            // + r*72 + j*16

  floatx4 zero4 = {0.f, 0.f, 0.f, 0.f};
  floatx4 O[4];
  float lp[4];  // per-thread partial l (reduced after the loop)
#pragma unroll
  for (int j = 0; j < 4; j++) O[j] = zero4;
#pragma unroll
  for (int r = 0; r < 4; r++) lp[r] = 0.f;

  const int ntt = (len + 63) >> 6;
  for (int tt = 0; tt < ntt; ++tt) {
    const int t0 = tt * 64;

    // ---- K B-frags from global: n = t0+j*16+col, k = ks*32+quad*8 ----
    half8 kb[2][4];
#pragma unroll
    for (int ks = 0; ks < 2; ks++)
#pragma unroll
      for (int j = 0; j < 4; j++)
        kb[ks][j] = *(const half8*)(kb_g + (t0 + j * 16 + col) * 64 +
                                    ks * 32 + quad * 8);

    // ---- raw scores = Q K^T; q carries 0.125*log2e ----
    floatx4 sc[4];
#pragma unroll
    for (int j = 0; j < 4; j++) sc[j] = zero4;
#pragma unroll
    for (int ks = 0; ks < 2; ks++)
#pragma unroll
      for (int j = 0; j < 4; j++)
        sc[j] = MFMA16(qf[ks], kb[ks][j], sc[j]);

    // ---- V B-frags issued EARLY (latency hidden under softmax) ----
    half8 vb[2][4];
#pragma unroll
    for (int ks = 0; ks < 2; ks++)
#pragma unroll
      for (int j = 0; j < 4; j++)
        vb[ks][j] = *(const half8*)(vb_g + (j * 16 + col) * 1024 + t0 +
                                    ks * 32 + quad * 8);

    if (t0 + 64 > len) {  // wave-uniform: only the last partial tile masks
#pragma unroll
      for (int j = 0; j < 4; j++) {
        bool inv = (t0 + j * 16 + col) >= len;
#pragma unroll
        for (int r = 0; r < 4; r++)
          if (inv) sc[j][r] = -3e38f;  // exp2 -> 0
      }
    }

    // ---- static softmax weights: p = exp2(score), f16-rounded for PV ----
#pragma unroll
    for (int r = 0; r < 4; r++) {
#pragma unroll
      for (int j = 0; j < 4; j++) {
        float e = __builtin_exp2f(sc[j][r]);
        Pw[p_wb + r * 72 + j * 16] = f2h(e);  // wave-private; no barrier
        lp[r] += e;
      }
    }

    // ---- O += P * V ----
#pragma unroll
    for (int ks = 0; ks < 2; ks++) {
      half8 pa = *(const half8*)(Pw + p_rd0 + ks * 32);
#pragma unroll
      for (int j = 0; j < 4; j++)
        O[j] = MFMA16(pa, vb[ks][j], O[j]);
    }
  }

  // ---- epilogue: reduce l, normalize; per-row override for invalid rows ----
  float l_r[4];
#pragma unroll
  for (int r = 0; r < 4; r++) l_r[r] = rowsum16(lp[r]);
#pragma unroll
  for (int r = 0; r < 4; r++) {
    int s = q0 + w * 16 + quad * 4 + r;
    float invl = 1.0f / l_r[r];
    bool valid = (s < len);
#pragma unroll
    for (int j = 0; j < 4; j++) {
      int d = j * 16 + col;
      float val = valid ? O[j][r] * invl : vsum[bh * 64 + d] * (1.0f / 1024.0f);
      out[(b * 1024 + s) * 1024 + h * 64 + d] = val;
    }
  }
}

// ---------------------------------------------------------------------------
// launch
// ---------------------------------------------------------------------------
extern "C" void kernel_launch(void* const* d_in, const int* in_sizes, int n_in,
                              void* d_out, int out_size, void* d_ws, size_t ws_size,
                              hipStream_t stream) {
  (void)in_sizes; (void)n_in; (void)out_size; (void)ws_size;
  const float* x  = (const float*)d_in[0];
  const float* Wq = (const float*)d_in[1];
  const float* bq = (const float*)d_in[2];
  const float* Wk = (const float*)d_in[3];
  const float* bk = (const float*)d_in[4];
  const float* Wv = (const float*)d_in[5];
  const float* bv = (const float*)d_in[6];
  const int* elen = (const int*)d_in[7];
  float* out = (float*)d_out;

  char* ws = (char*)d_ws;
  const size_t MB = 1024 * 1024;
  u16* xh  = (u16*)(ws + 0 * MB);
  u16* wqT = (u16*)(ws + 8 * MB);
  u16* wkT = (u16*)(ws + 10 * MB);
  u16* wvT = (u16*)(ws + 12 * MB);
  u16* qh  = (u16*)(ws + 14 * MB);
  u16* kh  = (u16*)(ws + 22 * MB);
  u16* vth = (u16*)(ws + 30 * MB);
  float* vsum = (float*)(ws + 38 * MB);  // 4096 floats

  k_prep<<<7168, 256, 0, stream>>>(x, xh, Wq, Wk, Wv, wqT, wkT, wvT, vsum);
  k_proj<<<dim3(32, 8, 3), 256, 0, stream>>>(xh, wqT, wkT, wvT, bq, bk, bv,
                                             qh, kh, vth, vsum);
  k_attn<<<1024, 256, 0, stream>>>(qh, kh, vth, vsum, elen, out);
}

// Round 14
// 151.470 us; speedup vs baseline: 1.4060x; 1.4060x over previous
//
#include <hip/hip_runtime.h>
#include <stdint.h>

// ---------------------------------------------------------------------------
// MultiAttentionHead: B=4 S=1024 E=1024 H=16 D=64, fp32 in/out.
// R14 == R11 REVERT (best known: 148.9 us). R12 (q-tile 128: occupancy loss
// offset window gain) and R13 (barrier-free direct-global frags: 128-B-stride
// scatter, 4x sector amplification, MfmaUtil 3.9%) both regressed -- the R11
// config is the measured optimum of this structure family:
//   k_attn: 64-row q-tile, double-buffered K/V LDS staging (1 barrier/iter),
//   40960 B LDS = 4 blocks/CU, batch-balance block remap, static softmax.
// Pipeline: ALL-FP16 single pass (R10). QK = q*k (q pre-scaled 0.125*log2e),
// p = exp2(raw score) f16-rounded for PV, l sums unrounded e. Rows s >=
// len[b]: uniform attn = mean(V) via vsum (fp32 from projection accs).
// Carried: R1 XOR swizzle (0 conflicts), R4 static softmax, R7 dbuf,
// R8 LDS-staged epilogue + direct V^T + fused prep.
// R9: k_proj BK=32 dbuf regressed -> BK=64 2-barrier kept.
// ---------------------------------------------------------------------------

using u16     = unsigned short;
using half8   = __attribute__((ext_vector_type(8))) _Float16;
using floatx4 = __attribute__((ext_vector_type(4))) float;

#define MFMA16(a, b, c) __builtin_amdgcn_mfma_f32_16x16x32_f16(a, b, c, 0, 0, 0)

__device__ __forceinline__ u16 f2h(float f) {  // f32 -> f16 bits (RTN)
  _Float16 h = (_Float16)f; u16 u; __builtin_memcpy(&u, &h, 2); return u;
}

// DPP rotate within aligned 16-lane rows (pure VALU; no LDS pipe).
template <int CTRL>
__device__ __forceinline__ float dppf(float v) {
  return __int_as_float(__builtin_amdgcn_update_dpp(
      0, __float_as_int(v), CTRL, 0xF, 0xF, true));
}
__device__ __forceinline__ float rowsum16(float v) {  // all-reduce sum, 16 lanes
  v += dppf<0x121>(v);
  v += dppf<0x122>(v);
  v += dppf<0x124>(v);
  v += dppf<0x128>(v);
  return v;
}

// async global->LDS DMA, 16B per lane. LDS dest must be wave-uniform base +
// lane*16 (no per-lane scatter) -- so bank swizzles permute the GLOBAL src.
__device__ __forceinline__ void async_cp16(void* lds, const void* g) {
  __builtin_amdgcn_global_load_lds(
      (__attribute__((address_space(1))) uint32_t*)(uintptr_t)g,
      (__attribute__((address_space(3))) uint32_t*)(uint32_t)(uintptr_t)lds,
      16, 0, 0);
}

// ---------------------------------------------------------------------------
// 1) prep (fused): blocks [0,4096): x -> f16 (block 0 zeroes vsum);
//    blocks [4096,7168): transpose W -> WT[n][k] f16.
// ---------------------------------------------------------------------------
__global__ void k_prep(const float* __restrict__ x, u16* __restrict__ xh,
                       const float* __restrict__ w0, const float* __restrict__ w1,
                       const float* __restrict__ w2,
                       u16* __restrict__ o0, u16* __restrict__ o1,
                       u16* __restrict__ o2, float* __restrict__ vsum) {
  __shared__ float t[32][33];
  const int bx = blockIdx.x;
  if (bx < 4096) {
    int i = (bx * 256 + threadIdx.x) * 4;
    float4 v = *(const float4*)(x + i);
    ushort4 hv;
    hv.x = f2h(v.x);
    hv.y = f2h(v.y);
    hv.z = f2h(v.z);
    hv.w = f2h(v.w);
    *(ushort4*)(xh + i) = hv;
    if (bx == 0) {  // zero vsum (4096 floats) for k_proj's atomics
      float4 z = {0.f, 0.f, 0.f, 0.f};
#pragma unroll
      for (int e = 0; e < 4; e++) ((float4*)vsum)[threadIdx.x * 4 + e] = z;
    }
    return;
  }
  const int id = bx - 4096;                 // 0..3071
  const int z = id >> 10, rem = id & 1023;
  const float* W = z == 0 ? w0 : (z == 1 ? w1 : w2);
  u16* oh = z == 0 ? o0 : (z == 1 ? o1 : o2);
  const int kb = (rem & 31) * 32, nb = (rem >> 5) * 32;
  const int tx = threadIdx.x & 31, ty = threadIdx.x >> 5;
  for (int r = ty; r < 32; r += 8) t[r][tx] = W[(kb + r) * 1024 + nb + tx];
  __syncthreads();
  for (int r = ty; r < 32; r += 8)
    oh[(nb + r) * 1024 + kb + tx] = f2h(t[tx][r]);
}

// ---------------------------------------------------------------------------
// 2) projection GEMM: C[4096][1024] = xh @ Wh + b, fp16 single pass,
//    128x128 tile, BK=64, 2-barrier K-loop (R9: dbuf regresses here).
//    LDS 32 KB staging / 34.8 KB epilogue tile -> 4 blocks/CU. Epilogue
//    stages C through LDS ([128][136]) for 16B stores. z=0/1 -> q/k f16 in
//    [B][H][S][D] (q pre-scaled by 0.125*log2e); z=2 -> V^T f16 + vsum.
// ---------------------------------------------------------------------------
__launch_bounds__(256, 4)
__global__ void k_proj(const u16* __restrict__ xh,
                       const u16* __restrict__ wqT, const u16* __restrict__ wkT,
                       const u16* __restrict__ wvT,
                       const float* __restrict__ bq, const float* __restrict__ bk,
                       const float* __restrict__ bv,
                       u16* __restrict__ qh, u16* __restrict__ kh,
                       u16* __restrict__ vth, float* __restrict__ vsum) {
  __shared__ u16 Sm[17408];  // K-loop: A@0, B@8192 ([128][64] f16 = 16 KB ea);
                             // epilogue: C tile [128][136] (34816 B)
  const int z = blockIdx.z;
  const u16* wT = z == 0 ? wqT : (z == 1 ? wkT : wvT);
  const float* bias = z == 0 ? bq : (z == 1 ? bk : bv);
  u16* oh = z == 0 ? qh : (z == 1 ? kh : vth);
  const float oscale = (z == 0) ? 0.18033688011112042f : 1.0f;  // 0.125*log2(e)

  const int tid = threadIdx.x, l = tid & 63, w = tid >> 6;
  const int quad = l >> 4, col = l & 15;
  const int m0 = blockIdx.x * 128, n0 = blockIdx.y * 128;
  const int wm = (w & 1) * 64, wn = (w >> 1) * 64;

  const int row0 = tid >> 3, ch = tid & 7;
  const int sc8 = (ch ^ (row0 & 7)) * 8;
  int gofs[4], lofs[4];
#pragma unroll
  for (int p = 0; p < 4; p++) {
    gofs[p] = (row0 + 32 * p) * 1024 + sc8;
    lofs[p] = (tid + p * 256) * 8;
  }

  const u16* Ag = xh + m0 * 1024;
  const u16* Bg = wT + n0 * 1024;

  int ar[2][4], br[2][4];
#pragma unroll
  for (int ks = 0; ks < 2; ks++) {
#pragma unroll
    for (int i = 0; i < 4; i++) {
      int r = wm + i * 16 + col;
      ar[ks][i] = r * 64 + (((ks * 4 + quad) ^ (r & 7)) * 8);
    }
#pragma unroll
    for (int j = 0; j < 4; j++) {
      int r = wn + j * 16 + col;
      br[ks][j] = r * 64 + (((ks * 4 + quad) ^ (r & 7)) * 8);
    }
  }

  floatx4 zero4 = {0.f, 0.f, 0.f, 0.f};
  floatx4 acc[4][4];
#pragma unroll
  for (int i = 0; i < 4; i++)
#pragma unroll
    for (int j = 0; j < 4; j++) acc[i][j] = zero4;

  for (int k0 = 0; k0 < 1024; k0 += 64) {
    __syncthreads();  // previous compute done before LDS overwrite
#pragma unroll
    for (int p = 0; p < 4; p++) async_cp16(Sm + lofs[p], Ag + gofs[p] + k0);
#pragma unroll
    for (int p = 0; p < 4; p++)
      async_cp16(Sm + 8192 + lofs[p], Bg + gofs[p] + k0);
    __syncthreads();  // DMA drained

#pragma unroll
    for (int ks = 0; ks < 2; ks++) {
      half8 fa[4], fb[4];
#pragma unroll
      for (int i = 0; i < 4; i++) fa[i] = *(const half8*)(Sm + ar[ks][i]);
#pragma unroll
      for (int j = 0; j < 4; j++)
        fb[j] = *(const half8*)(Sm + 8192 + br[ks][j]);
#pragma unroll
      for (int i = 0; i < 4; i++)
#pragma unroll
        for (int j = 0; j < 4; j++) acc[i][j] = MFMA16(fa[i], fb[j], acc[i][j]);
    }
  }

  // ---- epilogue: stage C tile in LDS ([128][136]) for coalesced stores ----
  const int bidx = m0 >> 10;     // batch index
  const int sbase = m0 & 1023;
  __syncthreads();  // all K-loop LDS reads done before overwrite

#pragma unroll
  for (int j = 0; j < 4; j++) {
    int nloc = wn + j * 16 + col;
    float bb = bias[n0 + nloc];
#pragma unroll
    for (int i = 0; i < 4; i++)
#pragma unroll
      for (int r = 0; r < 4; r++) {
        int mloc = wm + i * 16 + quad * 4 + r;
        Sm[mloc * 136 + nloc] = f2h((acc[i][j][r] + bb) * oscale);
      }
  }
  __syncthreads();

  if (z != 2) {
    // q/k: [bh][s][64] -- row-contiguous 16B chunks
#pragma unroll
    for (int k = 0; k < 8; k++) {
      int c = tid + k * 256;
      int mloc = c >> 4, n = (c & 15) * 8;
      int hh = (n0 + n) >> 6, d = (n0 + n) & 63;
      half8 vv = *(const half8*)(Sm + mloc * 136 + n);
      *(half8*)(oh + ((bidx * 16 + hh) * 1024 + sbase + mloc) * 64 + d) = vv;
    }
  } else {
    // V^T: [bh][d][1024] -- transposed read, s-contiguous 16B stores
#pragma unroll
    for (int k = 0; k < 8; k++) {
      int c = tid + k * 256;
      int nloc = c & 127, s0 = (c >> 7) * 8;
      int hh = (n0 + nloc) >> 6, d = (n0 + nloc) & 63;
      u16 tmp[8];
#pragma unroll
      for (int e = 0; e < 8; e++) tmp[e] = Sm[(s0 + e) * 136 + nloc];
      *(half8*)(vth + ((bidx * 16 + hh) * 64 + d) * 1024 + sbase + s0) =
          *(half8*)tmp;
    }
    // vsum partials from fp32 acc: vsum[bh*64+d] += sum over this block's s
#pragma unroll
    for (int j = 0; j < 4; j++) {
      int nloc = wn + j * 16 + col;
      float bb = bias[n0 + nloc];
      float part = 16.0f * bb;
#pragma unroll
      for (int i = 0; i < 4; i++)
#pragma unroll
        for (int r = 0; r < 4; r++) part += acc[i][j][r];
      part += __shfl_xor(part, 16, 64);  // reduce across quads (same n)
      part += __shfl_xor(part, 32, 64);
      if (quad == 0) {
        int hh = (n0 + nloc) >> 6, d = (n0 + nloc) & 63;
        unsafeAtomicAdd(vsum + (bidx * 16 + hh) * 64 + d, part);
      }
    }
  }
}

// ---------------------------------------------------------------------------
// Swizzled 64x64 f16 tile stage (global -> LDS via DMA).
// ---------------------------------------------------------------------------
__device__ __forceinline__ void stage64(u16* lds, const u16* g, int row_stride,
                                        int tid) {
#pragma unroll
  for (int p = 0; p < 2; p++) {
    int slot = (p * 256 + tid) * 8;  // element index; *2 = bytes
    int row = slot >> 6;
    int gp = (slot >> 3) & 7;
    int gl = gp ^ (row & 7);
    async_cp16(lds + slot, g + row * row_stride + gl * 8);
  }
}

// ---------------------------------------------------------------------------
// 3) flash attention, fp16, static softmax, double-buffered staging.
//    1-D grid of 1024, id remapped so each CU's 4 resident blocks span ALL
//    4 batches (b = (id + id>>8) & 3). Per iter: DMA tile t+1 into ping,
//    compute tile t from pong, ONE __syncthreads. P (f16) aliases Q's LDS
//    (wave-private rows). LDS 40960 B -> 4 blocks/CU.
// ---------------------------------------------------------------------------
__launch_bounds__(256)
__global__ void k_attn(const u16* __restrict__ qh_g,
                       const u16* __restrict__ kh_g,
                       const u16* __restrict__ vth_g,
                       const float* __restrict__ vsum, const int* __restrict__ elen,
                       float* __restrict__ out) {
  __shared__ u16 QP[4096];       // [64][64] swizzled: Q, then P (aliased)
  __shared__ u16 Bufs[2][8192];  // per buf: K@0, VT@4096 ([64][64] swizzled)
  const int tid = threadIdx.x, l = tid & 63, w = tid >> 6;
  const int quad = l >> 4, col = l & 15;
  // balance remap (bijective): each CU's {id, id+256, id+512, id+768}
  // resident set cycles through all 4 batches
  const int id = blockIdx.x;
  const int b = (id + (id >> 8)) & 3;
  const int h = (id >> 2) & 15;
  const int bh = b * 16 + h;
  const int q0 = ((id >> 6) & 15) * 64;
  const int len = elen[b];

  if (q0 >= len) {  // fully-invalid tile: uniform attention over ALL t (ref)
    float val = vsum[bh * 64 + l] * (1.0f / 1024.0f);
    float* op = out + (b * 1024 + q0) * 1024 + h * 64 + l;
    for (int r = w; r < 64; r += 4) op[r * 1024] = val;
    return;
  }

  const u16* kh_b  = kh_g + bh * 65536;
  const u16* vth_b = vth_g + bh * 65536;

  // prologue: stage Q + tile 0
  stage64(QP, qh_g + (bh * 1024 + q0) * 64, 64, tid);
  stage64(Bufs[0], kh_b, 64, tid);
  stage64(Bufs[0] + 4096, vth_b, 1024, tid);
  __syncthreads();

  half8 qf[2];  // persistent Q fragments (A-layout: m=lane&15, k=quad*8+j)
  {
    int qrow = w * 16 + col;
#pragma unroll
    for (int ks = 0; ks < 2; ks++)
      qf[ks] = *(const half8*)(QP + qrow * 64 +
                               (((ks * 4 + quad) ^ (qrow & 7)) * 8));
  }

  // fragment offsets (same swizzle for K and VT tiles)
  int kvo[2][4];
#pragma unroll
  for (int ks = 0; ks < 2; ks++)
#pragma unroll
    for (int j = 0; j < 4; j++) {
      int n = j * 16 + col;
      kvo[ks][j] = n * 64 + (((ks * 4 + quad) ^ (n & 7)) * 8);
    }
  int p_rd[2];
#pragma unroll
  for (int ks = 0; ks < 2; ks++) {
    int row = w * 16 + col;
    p_rd[ks] = row * 64 + (((ks * 4 + quad) ^ (row & 7)) * 8);
  }
  int p_wr[4][4];
#pragma unroll
  for (int r = 0; r < 4; r++) {
    int row = w * 16 + quad * 4 + r;
#pragma unroll
    for (int j = 0; j < 4; j++) {
      int cj = j * 2 + (col >> 3);
      p_wr[r][j] = row * 64 + ((cj ^ (row & 7)) * 8) + (col & 7);
    }
  }

  floatx4 zero4 = {0.f, 0.f, 0.f, 0.f};
  floatx4 O[4];
  float lp[4];  // per-thread partial l (reduced after the loop)
#pragma unroll
  for (int j = 0; j < 4; j++) O[j] = zero4;
#pragma unroll
  for (int r = 0; r < 4; r++) lp[r] = 0.f;

  const int ntt = (len + 63) >> 6;
  for (int tt = 0; tt < ntt; ++tt) {
    const int t0 = tt * 64;
    u16* cur = Bufs[tt & 1];
    if (tt + 1 < ntt) {  // overlap: DMA tile t+1 while computing tile t
      u16* nxt = Bufs[(tt + 1) & 1];
      const int t1 = t0 + 64;
      stage64(nxt, kh_b + t1 * 64, 64, tid);
      stage64(nxt + 4096, vth_b + t1, 1024, tid);
    }

    // ---- raw scores = Q K^T; q carries 0.125*log2e ----
    floatx4 sc[4];
#pragma unroll
    for (int j = 0; j < 4; j++) sc[j] = zero4;
#pragma unroll
    for (int ks = 0; ks < 2; ks++) {
#pragma unroll
      for (int j = 0; j < 4; j++) {
        half8 kb = *(const half8*)(cur + kvo[ks][j]);
        sc[j] = MFMA16(qf[ks], kb, sc[j]);
      }
    }

    if (t0 + 64 > len) {  // wave-uniform: only the last partial tile masks
#pragma unroll
      for (int j = 0; j < 4; j++) {
        bool inv = (t0 + j * 16 + col) >= len;
#pragma unroll
        for (int r = 0; r < 4; r++)
          if (inv) sc[j][r] = -3e38f;  // exp2 -> 0
      }
    }

    // ---- static softmax weights: p = exp2(score), f16-rounded for PV ----
#pragma unroll
    for (int r = 0; r < 4; r++) {
#pragma unroll
      for (int j = 0; j < 4; j++) {
        float e = __builtin_exp2f(sc[j][r]);
        QP[p_wr[r][j]] = f2h(e);  // wave-private rows; no barrier needed
        lp[r] += e;               // unrounded sum (mismatch <= 2^-12 rel)
      }
    }

    // ---- O += P * V ----
#pragma unroll
    for (int ks = 0; ks < 2; ks++) {
      half8 pa = *(const half8*)(QP + p_rd[ks]);
#pragma unroll
      for (int j = 0; j < 4; j++) {
        half8 vb = *(const half8*)(cur + 4096 + kvo[ks][j]);
        O[j] = MFMA16(pa, vb, O[j]);
      }
    }

    __syncthreads();  // drain next-tile DMA (overlapped) + sync compute
  }

  // ---- epilogue: reduce l, normalize; per-row override for invalid rows ----
  float l_r[4];
#pragma unroll
  for (int r = 0; r < 4; r++) l_r[r] = rowsum16(lp[r]);
#pragma unroll
  for (int r = 0; r < 4; r++) {
    int s = q0 + w * 16 + quad * 4 + r;
    float invl = 1.0f / l_r[r];
    bool valid = (s < len);
#pragma unroll
    for (int j = 0; j < 4; j++) {
      int d = j * 16 + col;
      float val = valid ? O[j][r] * invl : vsum[bh * 64 + d] * (1.0f / 1024.0f);
      out[(b * 1024 + s) * 1024 + h * 64 + d] = val;
    }
  }
}

// ---------------------------------------------------------------------------
// launch
// ---------------------------------------------------------------------------
extern "C" void kernel_launch(void* const* d_in, const int* in_sizes, int n_in,
                              void* d_out, int out_size, void* d_ws, size_t ws_size,
                              hipStream_t stream) {
  (void)in_sizes; (void)n_in; (void)out_size; (void)ws_size;
  const float* x  = (const float*)d_in[0];
  const float* Wq = (const float*)d_in[1];
  const float* bq = (const float*)d_in[2];
  const float* Wk = (const float*)d_in[3];
  const float* bk = (const float*)d_in[4];
  const float* Wv = (const float*)d_in[5];
  const float* bv = (const float*)d_in[6];
  const int* elen = (const int*)d_in[7];
  float* out = (float*)d_out;

  char* ws = (char*)d_ws;
  const size_t MB = 1024 * 1024;
  u16* xh  = (u16*)(ws + 0 * MB);
  u16* wqT = (u16*)(ws + 8 * MB);
  u16* wkT = (u16*)(ws + 10 * MB);
  u16* wvT = (u16*)(ws + 12 * MB);
  u16* qh  = (u16*)(ws + 14 * MB);
  u16* kh  = (u16*)(ws + 22 * MB);
  u16* vth = (u16*)(ws + 30 * MB);
  float* vsum = (float*)(ws + 38 * MB);  // 4096 floats

  k_prep<<<7168, 256, 0, stream>>>(x, xh, Wq, Wk, Wv, wqT, wkT, wvT, vsum);
  k_proj<<<dim3(32, 8, 3), 256, 0, stream>>>(xh, wqT, wkT, wvT, bq, bk, bv,
                                             qh, kh, vth, vsum);
  k_attn<<<1024, 256, 0, stream>>>(qh, kh, vth, vsum, elen, out);
}

// Round 15
// 150.044 us; speedup vs baseline: 1.4194x; 1.0095x over previous
//
#include <hip/hip_runtime.h>
#include <stdint.h>

// ---------------------------------------------------------------------------
// MultiAttentionHead: B=4 S=1024 E=1024 H=16 D=64, fp32 in/out.
// R15: k_attn 512-THREAD / 2-Q-TILE blocks -- R14's residual mystery
// (~6400 cyc/t-iter) matches per-CU global_load_lds drain throughput
// (4 blocks x 16 KB/iter-round); halve staged bytes per CU by sharing one
// K/V tile across 8 waves (128 q-rows) at CONSTANT 16 waves/CU (R12 lost
// its byte win by dropping to 12 waves). dbuf + 1 barrier/iter kept.
// Pipeline: ALL-FP16 single pass (R10). QK = q*k (q pre-scaled 0.125*log2e),
// p = exp2(raw score) f16-rounded for PV, l sums unrounded e. Rows s >=
// len[b]: uniform attn = mean(V) via vsum (fp32 from projection accs).
// Carried: R1 XOR swizzle (0 conflicts), R4 static softmax, R7 dbuf,
// R8 LDS-staged epilogue + direct V^T + fused prep, R11 balance remap.
// R9: k_proj BK=32 dbuf regressed -> BK=64 2-barrier kept.
// R13: direct-global frags regressed 2x (128-B-stride scatter) -- keep LDS.
// ---------------------------------------------------------------------------

using u16     = unsigned short;
using half8   = __attribute__((ext_vector_type(8))) _Float16;
using floatx4 = __attribute__((ext_vector_type(4))) float;

#define MFMA16(a, b, c) __builtin_amdgcn_mfma_f32_16x16x32_f16(a, b, c, 0, 0, 0)

__device__ __forceinline__ u16 f2h(float f) {  // f32 -> f16 bits (RTN)
  _Float16 h = (_Float16)f; u16 u; __builtin_memcpy(&u, &h, 2); return u;
}

// DPP rotate within aligned 16-lane rows (pure VALU; no LDS pipe).
template <int CTRL>
__device__ __forceinline__ float dppf(float v) {
  return __int_as_float(__builtin_amdgcn_update_dpp(
      0, __float_as_int(v), CTRL, 0xF, 0xF, true));
}
__device__ __forceinline__ float rowsum16(float v) {  // all-reduce sum, 16 lanes
  v += dppf<0x121>(v);
  v += dppf<0x122>(v);
  v += dppf<0x124>(v);
  v += dppf<0x128>(v);
  return v;
}

// async global->LDS DMA, 16B per lane. LDS dest must be wave-uniform base +
// lane*16 (no per-lane scatter) -- so bank swizzles permute the GLOBAL src.
__device__ __forceinline__ void async_cp16(void* lds, const void* g) {
  __builtin_amdgcn_global_load_lds(
      (__attribute__((address_space(1))) uint32_t*)(uintptr_t)g,
      (__attribute__((address_space(3))) uint32_t*)(uint32_t)(uintptr_t)lds,
      16, 0, 0);
}

// ---------------------------------------------------------------------------
// 1) prep (fused): blocks [0,4096): x -> f16 (block 0 zeroes vsum);
//    blocks [4096,7168): transpose W -> WT[n][k] f16.
// ---------------------------------------------------------------------------
__global__ void k_prep(const float* __restrict__ x, u16* __restrict__ xh,
                       const float* __restrict__ w0, const float* __restrict__ w1,
                       const float* __restrict__ w2,
                       u16* __restrict__ o0, u16* __restrict__ o1,
                       u16* __restrict__ o2, float* __restrict__ vsum) {
  __shared__ float t[32][33];
  const int bx = blockIdx.x;
  if (bx < 4096) {
    int i = (bx * 256 + threadIdx.x) * 4;
    float4 v = *(const float4*)(x + i);
    ushort4 hv;
    hv.x = f2h(v.x);
    hv.y = f2h(v.y);
    hv.z = f2h(v.z);
    hv.w = f2h(v.w);
    *(ushort4*)(xh + i) = hv;
    if (bx == 0) {  // zero vsum (4096 floats) for k_proj's atomics
      float4 z = {0.f, 0.f, 0.f, 0.f};
#pragma unroll
      for (int e = 0; e < 4; e++) ((float4*)vsum)[threadIdx.x * 4 + e] = z;
    }
    return;
  }
  const int id = bx - 4096;                 // 0..3071
  const int z = id >> 10, rem = id & 1023;
  const float* W = z == 0 ? w0 : (z == 1 ? w1 : w2);
  u16* oh = z == 0 ? o0 : (z == 1 ? o1 : o2);
  const int kb = (rem & 31) * 32, nb = (rem >> 5) * 32;
  const int tx = threadIdx.x & 31, ty = threadIdx.x >> 5;
  for (int r = ty; r < 32; r += 8) t[r][tx] = W[(kb + r) * 1024 + nb + tx];
  __syncthreads();
  for (int r = ty; r < 32; r += 8)
    oh[(nb + r) * 1024 + kb + tx] = f2h(t[tx][r]);
}

// ---------------------------------------------------------------------------
// 2) projection GEMM: C[4096][1024] = xh @ Wh + b, fp16 single pass,
//    128x128 tile, BK=64, 2-barrier K-loop (R9: dbuf regresses here).
//    LDS 32 KB staging / 34.8 KB epilogue tile -> 4 blocks/CU. Epilogue
//    stages C through LDS ([128][136]) for 16B stores. z=0/1 -> q/k f16 in
//    [B][H][S][D] (q pre-scaled by 0.125*log2e); z=2 -> V^T f16 + vsum.
// ---------------------------------------------------------------------------
__launch_bounds__(256, 4)
__global__ void k_proj(const u16* __restrict__ xh,
                       const u16* __restrict__ wqT, const u16* __restrict__ wkT,
                       const u16* __restrict__ wvT,
                       const float* __restrict__ bq, const float* __restrict__ bk,
                       const float* __restrict__ bv,
                       u16* __restrict__ qh, u16* __restrict__ kh,
                       u16* __restrict__ vth, float* __restrict__ vsum) {
  __shared__ u16 Sm[17408];  // K-loop: A@0, B@8192 ([128][64] f16 = 16 KB ea);
                             // epilogue: C tile [128][136] (34816 B)
  const int z = blockIdx.z;
  const u16* wT = z == 0 ? wqT : (z == 1 ? wkT : wvT);
  const float* bias = z == 0 ? bq : (z == 1 ? bk : bv);
  u16* oh = z == 0 ? qh : (z == 1 ? kh : vth);
  const float oscale = (z == 0) ? 0.18033688011112042f : 1.0f;  // 0.125*log2(e)

  const int tid = threadIdx.x, l = tid & 63, w = tid >> 6;
  const int quad = l >> 4, col = l & 15;
  const int m0 = blockIdx.x * 128, n0 = blockIdx.y * 128;
  const int wm = (w & 1) * 64, wn = (w >> 1) * 64;

  const int row0 = tid >> 3, ch = tid & 7;
  const int sc8 = (ch ^ (row0 & 7)) * 8;
  int gofs[4], lofs[4];
#pragma unroll
  for (int p = 0; p < 4; p++) {
    gofs[p] = (row0 + 32 * p) * 1024 + sc8;
    lofs[p] = (tid + p * 256) * 8;
  }

  const u16* Ag = xh + m0 * 1024;
  const u16* Bg = wT + n0 * 1024;

  int ar[2][4], br[2][4];
#pragma unroll
  for (int ks = 0; ks < 2; ks++) {
#pragma unroll
    for (int i = 0; i < 4; i++) {
      int r = wm + i * 16 + col;
      ar[ks][i] = r * 64 + (((ks * 4 + quad) ^ (r & 7)) * 8);
    }
#pragma unroll
    for (int j = 0; j < 4; j++) {
      int r = wn + j * 16 + col;
      br[ks][j] = r * 64 + (((ks * 4 + quad) ^ (r & 7)) * 8);
    }
  }

  floatx4 zero4 = {0.f, 0.f, 0.f, 0.f};
  floatx4 acc[4][4];
#pragma unroll
  for (int i = 0; i < 4; i++)
#pragma unroll
    for (int j = 0; j < 4; j++) acc[i][j] = zero4;

  for (int k0 = 0; k0 < 1024; k0 += 64) {
    __syncthreads();  // previous compute done before LDS overwrite
#pragma unroll
    for (int p = 0; p < 4; p++) async_cp16(Sm + lofs[p], Ag + gofs[p] + k0);
#pragma unroll
    for (int p = 0; p < 4; p++)
      async_cp16(Sm + 8192 + lofs[p], Bg + gofs[p] + k0);
    __syncthreads();  // DMA drained

#pragma unroll
    for (int ks = 0; ks < 2; ks++) {
      half8 fa[4], fb[4];
#pragma unroll
      for (int i = 0; i < 4; i++) fa[i] = *(const half8*)(Sm + ar[ks][i]);
#pragma unroll
      for (int j = 0; j < 4; j++)
        fb[j] = *(const half8*)(Sm + 8192 + br[ks][j]);
#pragma unroll
      for (int i = 0; i < 4; i++)
#pragma unroll
        for (int j = 0; j < 4; j++) acc[i][j] = MFMA16(fa[i], fb[j], acc[i][j]);
    }
  }

  // ---- epilogue: stage C tile in LDS ([128][136]) for coalesced stores ----
  const int bidx = m0 >> 10;     // batch index
  const int sbase = m0 & 1023;
  __syncthreads();  // all K-loop LDS reads done before overwrite

#pragma unroll
  for (int j = 0; j < 4; j++) {
    int nloc = wn + j * 16 + col;
    float bb = bias[n0 + nloc];
#pragma unroll
    for (int i = 0; i < 4; i++)
#pragma unroll
      for (int r = 0; r < 4; r++) {
        int mloc = wm + i * 16 + quad * 4 + r;
        Sm[mloc * 136 + nloc] = f2h((acc[i][j][r] + bb) * oscale);
      }
  }
  __syncthreads();

  if (z != 2) {
    // q/k: [bh][s][64] -- row-contiguous 16B chunks
#pragma unroll
    for (int k = 0; k < 8; k++) {
      int c = tid + k * 256;
      int mloc = c >> 4, n = (c & 15) * 8;
      int hh = (n0 + n) >> 6, d = (n0 + n) & 63;
      half8 vv = *(const half8*)(Sm + mloc * 136 + n);
      *(half8*)(oh + ((bidx * 16 + hh) * 1024 + sbase + mloc) * 64 + d) = vv;
    }
  } else {
    // V^T: [bh][d][1024] -- transposed read, s-contiguous 16B stores
#pragma unroll
    for (int k = 0; k < 8; k++) {
      int c = tid + k * 256;
      int nloc = c & 127, s0 = (c >> 7) * 8;
      int hh = (n0 + nloc) >> 6, d = (n0 + nloc) & 63;
      u16 tmp[8];
#pragma unroll
      for (int e = 0; e < 8; e++) tmp[e] = Sm[(s0 + e) * 136 + nloc];
      *(half8*)(vth + ((bidx * 16 + hh) * 64 + d) * 1024 + sbase + s0) =
          *(half8*)tmp;
    }
    // vsum partials from fp32 acc: vsum[bh*64+d] += sum over this block's s
#pragma unroll
    for (int j = 0; j < 4; j++) {
      int nloc = wn + j * 16 + col;
      float bb = bias[n0 + nloc];
      float part = 16.0f * bb;
#pragma unroll
      for (int i = 0; i < 4; i++)
#pragma unroll
        for (int r = 0; r < 4; r++) part += acc[i][j][r];
      part += __shfl_xor(part, 16, 64);  // reduce across quads (same n)
      part += __shfl_xor(part, 32, 64);
      if (quad == 0) {
        int hh = (n0 + nloc) >> 6, d = (n0 + nloc) & 63;
        unsafeAtomicAdd(vsum + (bidx * 16 + hh) * 64 + d, part);
      }
    }
  }
}

// ---------------------------------------------------------------------------
// Swizzled 64x64 f16 tile stage with 512 threads: 4096 u16 = one 16B issue
// per thread. Same XOR swizzle as before (slot row = tid>>3, chunk = tid&7).
// ---------------------------------------------------------------------------
__device__ __forceinline__ void stage_tile512(u16* lds, const u16* g,
                                              int row_stride, int tid) {
  int slot = tid * 8;
  int row = slot >> 6;
  int gl = (tid & 7) ^ (row & 7);
  async_cp16(lds + slot, g + row * row_stride + gl * 8);
}

// ---------------------------------------------------------------------------
// 3) flash attention, fp16, static softmax, dbuf, 512-THREAD 2-Q-TILE (R15).
//    Block: one (b,h), 128 q-rows; wave w in [0,8) owns rows w*16..w*16+15.
//    Per t-tile of 64: ONE staged K/V pair (16 KB) serves all 8 waves ->
//    per-CU staged bytes halve at constant 16 waves/CU. 1 barrier/iter.
//    P (f16, [128][64]) aliases Q's LDS (wave-private rows).
//    LDS: QP 16K + 2 x 16K = 48 KB -> 2 blocks/CU (grid-limited), 16 waves.
//    Grid 512, balance remap (resident pair spans 2 batches).
// ---------------------------------------------------------------------------
__launch_bounds__(512)
__global__ void k_attn(const u16* __restrict__ qh_g,
                       const u16* __restrict__ kh_g,
                       const u16* __restrict__ vth_g,
                       const float* __restrict__ vsum, const int* __restrict__ elen,
                       float* __restrict__ out) {
  __shared__ u16 QP[8192];       // [128][64] swizzled: Q, then P (aliased)
  __shared__ u16 Bufs[2][8192];  // per buf: K@0, VT@4096 ([64][64] swizzled)
  const int tid = threadIdx.x, l = tid & 63, w = tid >> 6;  // w in [0,8)
  const int quad = l >> 4, col = l & 15;
  // balance remap (bijective): resident set {id, id+256} spans 2 batches
  const int id = blockIdx.x;
  const int b = (id + (id >> 8)) & 3;
  const int h = (id >> 2) & 15;
  const int bh = b * 16 + h;
  const int q0 = ((id >> 6) & 7) * 128;
  const int len = elen[b];

  if (q0 >= len) {  // fully-invalid tile: uniform attention over ALL t (ref)
    float val = vsum[bh * 64 + l] * (1.0f / 1024.0f);
    float* op = out + (b * 1024 + q0) * 1024 + h * 64 + l;
    for (int r = w; r < 128; r += 8) op[r * 1024] = val;
    return;
  }

  const u16* kh_b  = kh_g + bh * 65536;
  const u16* vth_b = vth_g + bh * 65536;

  // prologue: stage Q (128 rows) + tile 0
  stage_tile512(QP,        qh_g + (bh * 1024 + q0) * 64, 64, tid);
  stage_tile512(QP + 4096, qh_g + (bh * 1024 + q0 + 64) * 64, 64, tid);
  stage_tile512(Bufs[0], kh_b, 64, tid);
  stage_tile512(Bufs[0] + 4096, vth_b, 1024, tid);
  __syncthreads();

  half8 qf[2];  // persistent Q fragments (A-layout: m=lane&15, k=quad*8+j)
  {
    int qrow = w * 16 + col;  // [0,128)
#pragma unroll
    for (int ks = 0; ks < 2; ks++)
      qf[ks] = *(const half8*)(QP + qrow * 64 +
                               (((ks * 4 + quad) ^ (qrow & 7)) * 8));
  }

  // fragment offsets (same swizzle for K and VT tiles; tile-local)
  int kvo[2][4];
#pragma unroll
  for (int ks = 0; ks < 2; ks++)
#pragma unroll
    for (int j = 0; j < 4; j++) {
      int n = j * 16 + col;
      kvo[ks][j] = n * 64 + (((ks * 4 + quad) ^ (n & 7)) * 8);
    }
  int p_rd[2];
#pragma unroll
  for (int ks = 0; ks < 2; ks++) {
    int row = w * 16 + col;
    p_rd[ks] = row * 64 + (((ks * 4 + quad) ^ (row & 7)) * 8);
  }
  int p_wr[4][4];
#pragma unroll
  for (int r = 0; r < 4; r++) {
    int row = w * 16 + quad * 4 + r;
#pragma unroll
    for (int j = 0; j < 4; j++) {
      int cj = j * 2 + (col >> 3);
      p_wr[r][j] = row * 64 + ((cj ^ (row & 7)) * 8) + (col & 7);
    }
  }

  floatx4 zero4 = {0.f, 0.f, 0.f, 0.f};
  floatx4 O[4];
  float lp[4];  // per-thread partial l (reduced after the loop)
#pragma unroll
  for (int j = 0; j < 4; j++) O[j] = zero4;
#pragma unroll
  for (int r = 0; r < 4; r++) lp[r] = 0.f;

  const int ntt = (len + 63) >> 6;
  for (int tt = 0; tt < ntt; ++tt) {
    const int t0 = tt * 64;
    u16* cur = Bufs[tt & 1];
    if (tt + 1 < ntt) {  // overlap: DMA tile t+1 while computing tile t
      u16* nxt = Bufs[(tt + 1) & 1];
      const int t1 = t0 + 64;
      stage_tile512(nxt, kh_b + t1 * 64, 64, tid);
      stage_tile512(nxt + 4096, vth_b + t1, 1024, tid);
    }

    // ---- raw scores = Q K^T; q carries 0.125*log2e ----
    floatx4 sc[4];
#pragma unroll
    for (int j = 0; j < 4; j++) sc[j] = zero4;
#pragma unroll
    for (int ks = 0; ks < 2; ks++) {
#pragma unroll
      for (int j = 0; j < 4; j++) {
        half8 kb = *(const half8*)(cur + kvo[ks][j]);
        sc[j] = MFMA16(qf[ks], kb, sc[j]);
      }
    }

    if (t0 + 64 > len) {  // wave-uniform: only the last partial tile masks
#pragma unroll
      for (int j = 0; j < 4; j++) {
        bool inv = (t0 + j * 16 + col) >= len;
#pragma unroll
        for (int r = 0; r < 4; r++)
          if (inv) sc[j][r] = -3e38f;  // exp2 -> 0
      }
    }

    // ---- static softmax weights: p = exp2(score), f16-rounded for PV ----
#pragma unroll
    for (int r = 0; r < 4; r++) {
#pragma unroll
      for (int j = 0; j < 4; j++) {
        float e = __builtin_exp2f(sc[j][r]);
        QP[p_wr[r][j]] = f2h(e);  // wave-private rows; no barrier needed
        lp[r] += e;               // unrounded sum (mismatch <= 2^-12 rel)
      }
    }

    // ---- O += P * V ----
#pragma unroll
    for (int ks = 0; ks < 2; ks++) {
      half8 pa = *(const half8*)(QP + p_rd[ks]);
#pragma unroll
      for (int j = 0; j < 4; j++) {
        half8 vb = *(const half8*)(cur + 4096 + kvo[ks][j]);
        O[j] = MFMA16(pa, vb, O[j]);
      }
    }

    __syncthreads();  // drain next-tile DMA (overlapped) + sync compute
  }

  // ---- epilogue: reduce l, normalize; per-row override for invalid rows ----
  float l_r[4];
#pragma unroll
  for (int r = 0; r < 4; r++) l_r[r] = rowsum16(lp[r]);
#pragma unroll
  for (int r = 0; r < 4; r++) {
    int s = q0 + w * 16 + quad * 4 + r;
    float invl = 1.0f / l_r[r];
    bool valid = (s < len);
#pragma unroll
    for (int j = 0; j < 4; j++) {
      int d = j * 16 + col;
      float val = valid ? O[j][r] * invl : vsum[bh * 64 + d] * (1.0f / 1024.0f);
      out[(b * 1024 + s) * 1024 + h * 64 + d] = val;
    }
  }
}

// ---------------------------------------------------------------------------
// launch
// ---------------------------------------------------------------------------
extern "C" void kernel_launch(void* const* d_in, const int* in_sizes, int n_in,
                              void* d_out, int out_size, void* d_ws, size_t ws_size,
                              hipStream_t stream) {
  (void)in_sizes; (void)n_in; (void)out_size; (void)ws_size;
  const float* x  = (const float*)d_in[0];
  const float* Wq = (const float*)d_in[1];
  const float* bq = (const float*)d_in[2];
  const float* Wk = (const float*)d_in[3];
  const float* bk = (const float*)d_in[4];
  const float* Wv = (const float*)d_in[5];
  const float* bv = (const float*)d_in[6];
  const int* elen = (const int*)d_in[7];
  float* out = (float*)d_out;

  char* ws = (char*)d_ws;
  const size_t MB = 1024 * 1024;
  u16* xh  = (u16*)(ws + 0 * MB);
  u16* wqT = (u16*)(ws + 8 * MB);
  u16* wkT = (u16*)(ws + 10 * MB);
  u16* wvT = (u16*)(ws + 12 * MB);
  u16* qh  = (u16*)(ws + 14 * MB);
  u16* kh  = (u16*)(ws + 22 * MB);
  u16* vth = (u16*)(ws + 30 * MB);
  float* vsum = (float*)(ws + 38 * MB);  // 4096 floats

  k_prep<<<7168, 256, 0, stream>>>(x, xh, Wq, Wk, Wv, wqT, wkT, wvT, vsum);
  k_proj<<<dim3(32, 8, 3), 256, 0, stream>>>(xh, wqT, wkT, wvT, bq, bk, bv,
                                             qh, kh, vth, vsum);
  k_attn<<<512, 512, 0, stream>>>(qh, kh, vth, vsum, elen, out);
}